// Round 2
// baseline (496.068 us; speedup 1.0000x reference)
//
#include <hip/hip_runtime.h>
#include <math.h>

#define NF 32

// ---- kernel 1: count out-degree (by src, for norm) and in-degree (by dst, for CSR)
__global__ void count_kernel(const int* __restrict__ src, const int* __restrict__ dst,
                             int* __restrict__ cnt_src, int* __restrict__ cnt_dst, int E) {
    int e = blockIdx.x * blockDim.x + threadIdx.x;
    if (e < E) {
        atomicAdd(&cnt_src[src[e]], 1);
        atomicAdd(&cnt_dst[dst[e]], 1);
    }
}

// ---- kernel 2: dis = deg>0 ? rsqrt(deg) : 0 --------------------------------
__global__ void dis_kernel(const int* __restrict__ cnt_src, float* __restrict__ dis, int N) {
    int i = blockIdx.x * blockDim.x + threadIdx.x;
    if (i < N) {
        int d = cnt_src[i];
        dis[i] = (d > 0) ? rsqrtf((float)d) : 0.0f;
    }
}

// ---- scan (exclusive) of cnt_dst: A) per-block inclusive, B) block sums, C) combine
__global__ void scanA_kernel(const int* __restrict__ cnt, int* __restrict__ incl,
                             int* __restrict__ bsum, int n) {
    __shared__ int s[256];
    int tid = threadIdx.x;
    int i = blockIdx.x * 256 + tid;
    s[tid] = (i < n) ? cnt[i] : 0;
    __syncthreads();
    for (int o = 1; o < 256; o <<= 1) {
        int t = (tid >= o) ? s[tid - o] : 0;
        __syncthreads();
        s[tid] += t;
        __syncthreads();
    }
    if (i < n) incl[i] = s[tid];
    if (tid == 255) bsum[blockIdx.x] = s[255];
}

__global__ void scanB_kernel(int* __restrict__ bsum, int nb) {
    __shared__ int s[512];
    int tid = threadIdx.x;
    s[tid] = (tid < nb) ? bsum[tid] : 0;
    __syncthreads();
    for (int o = 1; o < 512; o <<= 1) {
        int t = (tid >= o) ? s[tid - o] : 0;
        __syncthreads();
        s[tid] += t;
        __syncthreads();
    }
    if (tid < nb) bsum[tid] = (tid == 0) ? 0 : s[tid - 1];  // exclusive
}

__global__ void scanC_kernel(const int* __restrict__ incl, const int* __restrict__ cnt,
                             const int* __restrict__ bsum, int* __restrict__ cur, int n) {
    int i = blockIdx.x * 256 + threadIdx.x;
    if (i < n) cur[i] = incl[i] - cnt[i] + bsum[i >> 8];  // exclusive start
}

// ---- kernel 3: fill CSR buckets (cur advances to end offsets) --------------
__global__ void fill_kernel(const int* __restrict__ src, const int* __restrict__ dst,
                            int* __restrict__ cur, int* __restrict__ bucket, int E) {
    int e = blockIdx.x * blockDim.x + threadIdx.x;
    if (e < E) {
        int pos = atomicAdd(&cur[dst[e]], 1);
        bucket[pos] = src[e];
    }
}

// ---- kernel 4: fused gather + gates + readout ------------------------------
// block = 256 threads = 8 nodes x 32 feature-lanes
__global__ __launch_bounds__(256) void gate_gather_kernel(
    const float* __restrict__ x, const int* __restrict__ bucket,
    const int* __restrict__ cur, const int* __restrict__ cnt_dst,
    const float* __restrict__ dis,
    const float* __restrict__ Wxz0, const float* __restrict__ Wxz1,
    const float* __restrict__ bxz,  const float* __restrict__ bhz,
    const float* __restrict__ Wxh0, const float* __restrict__ Wxh1,
    const float* __restrict__ bxh,  const float* __restrict__ bhh,
    const float* __restrict__ Wl,   const float* __restrict__ bl,
    float* __restrict__ out, int N)
{
    __shared__ float sWz0[NF * NF], sWz1[NF * NF], sWh0[NF * NF], sWh1[NF * NF];
    __shared__ float sbz[NF], sbh[NF], sWl[NF];
    __shared__ float sx[8][NF + 1], st[8][NF + 1];

    int t = threadIdx.x;
    for (int i = t; i < NF * NF; i += 256) {
        sWz0[i] = Wxz0[i];
        sWz1[i] = Wxz1[i];
        sWh0[i] = Wxh0[i];
        sWh1[i] = Wxh1[i];
    }
    if (t < NF) {
        sbz[t] = bxz[t] + bhz[t];
        sbh[t] = bxh[t] + bhh[t];
        sWl[t] = Wl[t];
    }

    int nl = t >> 5;          // node within block (0..7)
    int f  = t & 31;          // feature lane (0..31)
    int node = blockIdx.x * 8 + nl;

    if (node < N) {
        sx[nl][f] = x[node * NF + f];
        // gather: tx1[node] = -dis[node] * sum_e dis[src_e] * x[src_e]
        int end   = cur[node];
        int start = end - cnt_dst[node];
        float acc = 0.0f;
        for (int j = start; j < end; ++j) {
            int s = bucket[j];
            acc += dis[s] * x[s * NF + f];
        }
        st[nl][f] = -dis[node] * acc;
    }
    __syncthreads();
    if (node >= N) return;

    float az = sbz[f];
    float ah = sbh[f];
    #pragma unroll
    for (int k = 0; k < NF; ++k) {
        float xv = sx[nl][k];
        float tv = st[nl][k];
        az += xv * sWz0[k * NF + f] + tv * sWz1[k * NF + f];
        ah += xv * sWh0[k * NF + f] + tv * sWh1[k * NF + f];
    }

    float z  = 1.0f / (1.0f + expf(-az));
    float ht = tanhf(ah);
    float h  = (1.0f - z) * ht;
    float r  = fmaxf(h, 0.0f);
    float c  = r * sWl[f];

    #pragma unroll
    for (int m = 16; m >= 1; m >>= 1) c += __shfl_xor(c, m, 64);

    if (f == 0) out[node] = c + bl[0];
}

extern "C" void kernel_launch(void* const* d_in, const int* in_sizes, int n_in,
                              void* d_out, int out_size, void* d_ws, size_t ws_size,
                              hipStream_t stream) {
    const float* x    = (const float*)d_in[0];
    const int*   edge = (const int*)d_in[1];   // [2, E]: src row then dst row
    const float* Wxz0 = (const float*)d_in[2];
    const float* Wxz1 = (const float*)d_in[3];
    const float* bxz  = (const float*)d_in[4];
    const float* bhz  = (const float*)d_in[7];
    const float* Wxh0 = (const float*)d_in[14];
    const float* Wxh1 = (const float*)d_in[15];
    const float* bxh  = (const float*)d_in[16];
    const float* bhh  = (const float*)d_in[19];
    const float* Wl   = (const float*)d_in[20];
    const float* bl   = (const float*)d_in[21];
    float* out = (float*)d_out;

    int N = in_sizes[0] / NF;
    int E = in_sizes[1] / 2;
    const int* src = edge;
    const int* dst = edge + E;

    // workspace layout (4B elems):
    // cnt_src[N] | cnt_dst[N] | dis[N] | incl[N] | cur[N] | bsum[512] | bucket[E]
    int*   cnt_src = (int*)d_ws;
    int*   cnt_dst = cnt_src + N;
    float* dis     = (float*)(cnt_dst + N);
    int*   incl    = (int*)(dis + N);
    int*   cur     = incl + N;
    int*   bsum    = cur + N;
    int*   bucket  = bsum + 512;

    hipMemsetAsync(d_ws, 0, (size_t)2 * N * sizeof(int), stream);

    int eb = (E + 255) / 256;
    int nb = (N + 255) / 256;

    count_kernel<<<eb, 256, 0, stream>>>(src, dst, cnt_src, cnt_dst, E);
    dis_kernel<<<nb, 256, 0, stream>>>(cnt_src, dis, N);

    scanA_kernel<<<nb, 256, 0, stream>>>(cnt_dst, incl, bsum, N);
    scanB_kernel<<<1, 512, 0, stream>>>(bsum, nb);
    scanC_kernel<<<nb, 256, 0, stream>>>(incl, cnt_dst, bsum, cur, N);

    fill_kernel<<<eb, 256, 0, stream>>>(src, dst, cur, bucket, E);

    gate_gather_kernel<<<(N + 7) / 8, 256, 0, stream>>>(
        x, bucket, cur, cnt_dst, dis,
        Wxz0, Wxz1, bxz, bhz, Wxh0, Wxh1, bxh, bhh, Wl, bl, out, N);
}